// Round 5
// baseline (857.647 us; speedup 1.0000x reference)
//
#include <hip/hip_runtime.h>
#include <cstdint>
#include <cstddef>

using u16 = unsigned short;

typedef __attribute__((ext_vector_type(4))) int   i32x4;
typedef __attribute__((ext_vector_type(4))) float f32x4;
typedef __attribute__((ext_vector_type(8))) short s16x8;

__device__ __forceinline__ u16 f2b(float f) {
  union { float f; unsigned u; } x; x.f = f;
  unsigned r = x.u + 0x7fffu + ((x.u >> 16) & 1u);   // RNE
  return (u16)(r >> 16);
}

// ---------------- elementwise cvt f32 -> bf16 (float4 vectorized) ----------------
__global__ __launch_bounds__(256) void cvt_bf16_kernel(const float* __restrict__ src,
                                                       u16* __restrict__ dst, int n4) {
  int i = blockIdx.x * 256 + threadIdx.x;
  if (i >= n4) return;
  float4 v = ((const float4*)src)[i];
  ((ushort4*)dst)[i] = make_ushort4(f2b(v.x), f2b(v.y), f2b(v.z), f2b(v.w));
}

// ---------------- transpose + cvt: dst[c][r] = (bf16)src[r][c] ----------------
__global__ __launch_bounds__(256) void transpose_cvt_kernel(const float* __restrict__ src,
                                                            u16* __restrict__ dst,
                                                            int R, int C) {
  __shared__ float t[32][33];
  const int tx = threadIdx.x & 31, ty = threadIdx.x >> 5;
  const int c0 = blockIdx.x * 32, r0 = blockIdx.y * 32;
  #pragma unroll
  for (int k = 0; k < 32; k += 8)
    t[ty + k][tx] = src[(size_t)(r0 + ty + k) * C + c0 + tx];
  __syncthreads();
  #pragma unroll
  for (int k = 0; k < 32; k += 8)
    dst[(size_t)(c0 + ty + k) * R + r0 + tx] = f2b(t[tx][ty + k]);
}

// ---------------- bf16 MFMA GEMM 128x128 tile (for N=4096 FFN1) ----------------
__global__ __launch_bounds__(256) void gemm_bt(const u16* __restrict__ A,
                                               const u16* __restrict__ B,
                                               float* __restrict__ C,
                                               int M, int N, int K) {
  (void)M;
  __shared__ __align__(16) u16 As[128 * 32];
  __shared__ __align__(16) u16 Bs[128 * 32];
  const int tid  = threadIdx.x;
  const int wid  = tid >> 6;
  const int lane = tid & 63;
  const int m0 = blockIdx.y * 128;
  const int n0 = blockIdx.x * 128;
  const int wm = (wid >> 1) * 64;
  const int wn = (wid & 1) * 64;

  const int srow = wid * 32 + (lane >> 2);
  const int scol = (lane & 3) * 8;
  const int fr = lane & 15;
  const int fk = (lane >> 4) * 8;

  f32x4 acc[4][4] = {};

  for (int k0 = 0; k0 < K; k0 += 32) {
    const u16* ga0 = A + (size_t)(m0 + srow) * K + k0 + scol;
    const u16* ga1 = ga0 + (size_t)16 * K;
    const u16* gb0 = B + (size_t)(n0 + srow) * K + k0 + scol;
    const u16* gb1 = gb0 + (size_t)16 * K;
    __builtin_amdgcn_global_load_lds((const __attribute__((address_space(1))) void*)ga0,
                                     (__attribute__((address_space(3))) void*)(As + wid * 1024), 16, 0, 0);
    __builtin_amdgcn_global_load_lds((const __attribute__((address_space(1))) void*)ga1,
                                     (__attribute__((address_space(3))) void*)(As + wid * 1024 + 512), 16, 0, 0);
    __builtin_amdgcn_global_load_lds((const __attribute__((address_space(1))) void*)gb0,
                                     (__attribute__((address_space(3))) void*)(Bs + wid * 1024), 16, 0, 0);
    __builtin_amdgcn_global_load_lds((const __attribute__((address_space(1))) void*)gb1,
                                     (__attribute__((address_space(3))) void*)(Bs + wid * 1024 + 512), 16, 0, 0);
    __syncthreads();

    i32x4 av[4], bv[4];
    #pragma unroll
    for (int i = 0; i < 4; ++i)
      av[i] = *(const i32x4*)(As + (wm + i * 16 + fr) * 32 + fk);
    #pragma unroll
    for (int j = 0; j < 4; ++j)
      bv[j] = *(const i32x4*)(Bs + (wn + j * 16 + fr) * 32 + fk);

    #pragma unroll
    for (int i = 0; i < 4; ++i) {
      #pragma unroll
      for (int j = 0; j < 4; ++j) {
        asm volatile("v_mfma_f32_16x16x32_bf16 %0, %1, %2, %0"
                     : "+v"(acc[i][j]) : "v"(av[i]), "v"(bv[j]));
      }
    }
    __syncthreads();
  }
  asm volatile("s_nop 7\ns_nop 7\ns_nop 7" : : :);

  const int er = (lane >> 4) * 4;
  #pragma unroll
  for (int i = 0; i < 4; ++i) {
    #pragma unroll
    for (int j = 0; j < 4; ++j) {
      const int r0 = m0 + wm + i * 16 + er;
      const int c  = n0 + wn + j * 16 + fr;
      #pragma unroll
      for (int r = 0; r < 4; ++r)
        C[(size_t)(r0 + r) * N + c] = acc[i][j][r];
    }
  }
}

// ---------------- bf16 MFMA GEMM 64x128 tile (for N=1024 shapes: 2x the grid) ----------
__global__ __launch_bounds__(256) void gemm_bt64(const u16* __restrict__ A,
                                                 const u16* __restrict__ B,
                                                 float* __restrict__ C,
                                                 int M, int N, int K) {
  (void)M;
  __shared__ __align__(16) u16 As[64 * 32];
  __shared__ __align__(16) u16 Bs[128 * 32];
  const int tid  = threadIdx.x;
  const int wid  = tid >> 6;
  const int lane = tid & 63;
  const int m0 = blockIdx.y * 64;
  const int n0 = blockIdx.x * 128;
  const int wm = (wid >> 1) * 32;
  const int wn = (wid & 1) * 64;

  const int srowA = wid * 16 + (lane >> 2);
  const int srowB = wid * 32 + (lane >> 2);
  const int scol = (lane & 3) * 8;
  const int fr = lane & 15;
  const int fk = (lane >> 4) * 8;

  f32x4 acc[2][4] = {};

  for (int k0 = 0; k0 < K; k0 += 32) {
    const u16* ga  = A + (size_t)(m0 + srowA) * K + k0 + scol;
    const u16* gb0 = B + (size_t)(n0 + srowB) * K + k0 + scol;
    const u16* gb1 = gb0 + (size_t)16 * K;
    __builtin_amdgcn_global_load_lds((const __attribute__((address_space(1))) void*)ga,
                                     (__attribute__((address_space(3))) void*)(As + wid * 512), 16, 0, 0);
    __builtin_amdgcn_global_load_lds((const __attribute__((address_space(1))) void*)gb0,
                                     (__attribute__((address_space(3))) void*)(Bs + wid * 1024), 16, 0, 0);
    __builtin_amdgcn_global_load_lds((const __attribute__((address_space(1))) void*)gb1,
                                     (__attribute__((address_space(3))) void*)(Bs + wid * 1024 + 512), 16, 0, 0);
    __syncthreads();

    i32x4 av[2], bv[4];
    #pragma unroll
    for (int i = 0; i < 2; ++i)
      av[i] = *(const i32x4*)(As + (wm + i * 16 + fr) * 32 + fk);
    #pragma unroll
    for (int j = 0; j < 4; ++j)
      bv[j] = *(const i32x4*)(Bs + (wn + j * 16 + fr) * 32 + fk);

    #pragma unroll
    for (int i = 0; i < 2; ++i) {
      #pragma unroll
      for (int j = 0; j < 4; ++j) {
        asm volatile("v_mfma_f32_16x16x32_bf16 %0, %1, %2, %0"
                     : "+v"(acc[i][j]) : "v"(av[i]), "v"(bv[j]));
      }
    }
    __syncthreads();
  }
  asm volatile("s_nop 7\ns_nop 7\ns_nop 7" : : :);

  const int er = (lane >> 4) * 4;
  #pragma unroll
  for (int i = 0; i < 2; ++i) {
    #pragma unroll
    for (int j = 0; j < 4; ++j) {
      const int r0 = m0 + wm + i * 16 + er;
      const int c  = n0 + wn + j * 16 + fr;
      #pragma unroll
      for (int r = 0; r < 4; ++r)
        C[(size_t)(r0 + r) * N + c] = acc[i][j][r];
    }
  }
}

// ---------------- per-head permute: dst[bn][row][64] bf16 from src[(row*2+b)*1024+n*64+d] -
__global__ __launch_bounds__(256) void headperm_kernel(const float* __restrict__ src,
                                                       u16* __restrict__ dst,
                                                       int Rsrc, int Rdst) {
  const int bn = blockIdx.y, b = bn >> 4, n = bn & 15;
  const int row = blockIdx.x * 16 + (threadIdx.x >> 4);
  const int d4 = (threadIdx.x & 15) * 4;
  if (row >= Rdst) return;
  u16* dp = dst + ((size_t)bn * Rdst + row) * 64 + d4;
  if (row < Rsrc) {
    float4 v = *(const float4*)(src + ((size_t)row * 2 + b) * 1024 + n * 64 + d4);
    *(ushort4*)dp = make_ushort4(f2b(v.x), f2b(v.y), f2b(v.z), f2b(v.w));
  } else {
    *(ushort4*)dp = make_ushort4(0, 0, 0, 0);
  }
}

// ---------------- rowdot: out[bn*ostride + ooff + row] = bias[n].mat_row --------
__global__ __launch_bounds__(256) void rowdot_kernel(const float* __restrict__ mat,
                                                     const float* __restrict__ bias,
                                                     float* __restrict__ out, int tasks,
                                                     int ostride, int ooff) {
  const int task = blockIdx.x * 4 + (threadIdx.x >> 6);
  const int lane = threadIdx.x & 63;
  if (task >= tasks) return;
  const int jb = task >> 4, n = task & 15;
  float v = mat[(size_t)jb * 1024 + n * 64 + lane] * bias[n * 64 + lane];
  #pragma unroll
  for (int o = 32; o; o >>= 1) v += __shfl_xor(v, o);
  if (lane == 0) out[(size_t)((jb & 1) * 16 + n) * ostride + ooff + (jb >> 1)] = v;
}

// ---------------- ef1: out[task*2+s] = sum_d (q[ib,n,d] + rsb[n,d]) * seg[s,n,d] ----------
__global__ __launch_bounds__(256) void ef1_kernel(const float* __restrict__ q,
                                                  const float* __restrict__ rsb,
                                                  const float* __restrict__ seg,
                                                  float* __restrict__ out, int tasks) {
  const int task = blockIdx.x * 4 + (threadIdx.x >> 6);
  const int lane = threadIdx.x & 63;
  if (task >= tasks) return;
  const int ib = task >> 4, n = task & 15;
  const float qv = q[(size_t)ib * 1024 + n * 64 + lane] + rsb[n * 64 + lane];
  float a = qv * seg[n * 64 + lane];
  float c = qv * seg[1024 + n * 64 + lane];
  #pragma unroll
  for (int o = 32; o; o >>= 1) { a += __shfl_xor(a, o); c += __shfl_xor(c, o); }
  if (lane == 0) { out[(size_t)task * 2] = a; out[(size_t)task * 2 + 1] = c; }
}

// ---------------- tseg: t[b*1024 + j] = seg_mat[0, j, b, 1] ----
__global__ __launch_bounds__(256) void tseg_kernel(const float* __restrict__ segmat,
                                                   float* __restrict__ t) {
  const int idx = blockIdx.x * 256 + threadIdx.x;
  if (idx >= 2048) return;
  const int b = idx >> 10, j = idx & 1023;
  t[idx] = segmat[((size_t)j * 2 + b) * 2 + 1];
}

// ---------------- V transpose: vt[(bn*64+d)*1024 + j] = bf16(vh[(j*2+b)*1024 + n*64 + d]) -
__global__ __launch_bounds__(256) void vtrans_kernel(const float* __restrict__ vh,
                                                     u16* __restrict__ vt) {
  __shared__ float t[64][65];
  const int bn = blockIdx.y, b = bn >> 4, n = bn & 15;
  const int j0 = blockIdx.x * 64;
  const int r = threadIdx.x >> 2, c16 = (threadIdx.x & 3) * 16;
  const float* src = vh + ((size_t)(j0 + r) * 2 + b) * 1024 + n * 64 + c16;
  #pragma unroll
  for (int k = 0; k < 16; k += 4)
    *(float4*)&t[r][c16 + k] = *(const float4*)(src + k);
  __syncthreads();
  u16 v[16];
  #pragma unroll
  for (int k = 0; k < 16; ++k) v[k] = f2b(t[c16 + k][r]);
  u16* dst = vt + ((size_t)bn * 64 + r) * 1024 + j0 + c16;
  #pragma unroll
  for (int k = 0; k < 16; k += 8)
    *(uint4*)(dst + k) = *(const uint4*)&v[k];
}

// ---------------- MFMA relative attention: 4 waves = one 64-row i-block ------
// grid (16 i64-tiles, 32 bn), 256 threads. Wave w owns q-rows it64*64 + w*16 + il.
// All 4 waves share the same j-range -> K/Kr/V lines de-duped in L1/L2.
__global__ __launch_bounds__(256) void attn_mfma_kernel(
    const u16* __restrict__ QP, const u16* __restrict__ KP,
    const u16* __restrict__ KrP, const u16* __restrict__ Vtb,
    const float* __restrict__ rwk2, const float* __restrict__ rrk2,
    const float* __restrict__ ef1, const float* __restrict__ tsegp,
    u16* __restrict__ Ovec, int isG) {
  __shared__ __align__(16) float bdts[4][16][84];   // per-wave band (80 rows used)
  __shared__ __align__(16) u16   ps[4][1024];       // per-wave 16x64 bf16 P^T, swizzled

  const int w = threadIdx.x >> 6, lane = threadIdx.x & 63;
  const int il = lane & 15, g = lane >> 4;
  const int x = blockIdx.x;
  const int it64 = isG ? (x == 0 ? 0 : 16 - x) : 15 - x;   // longest blocks first
  const int i0 = it64 * 64 + w * 16;                       // this wave's 16-row base
  const int bn = blockIdx.y, b = bn >> 4, n = bn & 15;
  const int iglob = i0 + il;

  // Q as B-frags (col = q-row, k = d), bf16 per-head layout
  s16x8 qf[2];
  {
    const u16* qrow = QP + ((size_t)bn * 1024 + iglob) * 64;
    qf[0] = *(const s16x8*)(qrow + g * 8);
    qf[1] = *(const s16x8*)(qrow + 32 + g * 8);
  }
  const float2 efv = *(const float2*)(ef1 + (((size_t)iglob * 2 + b) * 16 + n) * 2);
  const float e0 = efv.x, ed = efv.y - efv.x;
  const float ti = tsegp[b * 1024 + iglob];

  f32x4 o[4] = {};
  float m = -1e30f, l = 0.f;

  const int NT = (isG && it64 == 0) ? 16 : (it64 + 1);     // block-uniform
  const u16* kbase  = KP  + (size_t)bn * 1024 * 64 + g * 8;
  const u16* krbase = KrP + (size_t)bn * 2056 * 64 + g * 8;
  const u16* vbase  = Vtb + ((size_t)bn * 64 + il) * 1024 + g * 8;
  const float* rwkp = rwk2 + (size_t)bn * 1024;
  const float* rrkp = rrk2 + (size_t)bn * 2056 + 3;
  const float* tjp  = tsegp + b * 1024;
  char* pbase = (char*)&ps[w][0];
  const int pwb = il * 128;
  const int swz = (il & 7) << 4;

  for (int jt = 0; jt < NT; ++jt) {
    const int j0 = jt * 64;
    const int base = 1009 + j0 - i0;   // kr row of band idx 0; band idx = jl - il + 15 in [0,78]

    // --- AC: S^T[j, i] ---
    f32x4 sT[4] = {};
    #pragma unroll
    for (int jf = 0; jf < 4; ++jf) {
      const u16* kp = kbase + (size_t)(j0 + jf * 16 + il) * 64;
      s16x8 k0 = *(const s16x8*)kp;
      s16x8 k1 = *(const s16x8*)(kp + 32);
      sT[jf] = __builtin_amdgcn_mfma_f32_16x16x32_bf16(k0, qf[0], sT[jf], 0, 0, 0);
      sT[jf] = __builtin_amdgcn_mfma_f32_16x16x32_bf16(k1, qf[1], sT[jf], 0, 0, 0);
    }

    // --- V frags early (overlap with BD + softmax) ---
    s16x8 va[4][2];
    #pragma unroll
    for (int df = 0; df < 4; ++df) {
      const u16* vp = vbase + (size_t)df * 16384 + j0;
      va[df][0] = *(const s16x8*)vp;
      va[df][1] = *(const s16x8*)(vp + 32);
    }

    // --- BD band (80 kr rows, 5 frags) + rrk prefold -> LDS ---
    #pragma unroll
    for (int jf5 = 0; jf5 < 5; ++jf5) {
      const u16* kp = krbase + (size_t)(base + jf5 * 16 + il) * 64;
      s16x8 k0 = *(const s16x8*)kp;
      s16x8 k1 = *(const s16x8*)(kp + 32);
      f32x4 bdt = {};
      bdt = __builtin_amdgcn_mfma_f32_16x16x32_bf16(k0, qf[0], bdt, 0, 0, 0);
      bdt = __builtin_amdgcn_mfma_f32_16x16x32_bf16(k1, qf[1], bdt, 0, 0, 0);
      const float4 rr = *(const float4*)(rrkp + base + jf5 * 16 + 4 * g);
      bdt[0] += rr.x; bdt[1] += rr.y; bdt[2] += rr.z; bdt[3] += rr.w;
      *(f32x4*)&bdts[w][il][jf5 * 16 + 4 * g] = bdt;
    }
    asm volatile("s_waitcnt lgkmcnt(0)" ::: "memory");
    __builtin_amdgcn_sched_barrier(0);

    // --- assemble scores (rel-shift gather + rwk + ef + analytic mask) ---
    float sc[4][4];
    float tmax = -INFINITY;
    #pragma unroll
    for (int jf = 0; jf < 4; ++jf) {
      const float4 rw = *(const float4*)(rwkp + j0 + jf * 16 + 4 * g);
      const float4 tj = *(const float4*)(tjp + j0 + jf * 16 + 4 * g);
      #pragma unroll
      for (int r = 0; r < 4; ++r) {
        const int jl = jf * 16 + 4 * g + r;
        const float bd = bdts[w][il][jl - il + 15];
        const float tjv = r == 0 ? tj.x : r == 1 ? tj.y : r == 2 ? tj.z : tj.w;
        const float rwv = r == 0 ? rw.x : r == 1 ? rw.y : r == 2 ? rw.z : rw.w;
        float s = (sT[jf][r] + bd + rwv + e0 + fabsf(ti - tjv) * ed) * 0.125f;
        const int j = j0 + jl;
        const bool masked = isG ? (j >= iglob) : (j > iglob);
        s = masked ? -1e30f : s;
        sc[jf][r] = s;
        tmax = fmaxf(tmax, s);
      }
    }
    tmax = fmaxf(tmax, __shfl_xor(tmax, 16));
    tmax = fmaxf(tmax, __shfl_xor(tmax, 32));
    const float mn = fmaxf(m, tmax);
    const float scl = __expf(m - mn);
    float psum = 0.f;
    u16 pb[16];
    #pragma unroll
    for (int jf = 0; jf < 4; ++jf) {
      #pragma unroll
      for (int r = 0; r < 4; ++r) {
        const float p = __expf(sc[jf][r] - mn);
        psum += p;
        pb[jf * 4 + r] = f2b(p);
      }
    }
    psum += __shfl_xor(psum, 16);
    psum += __shfl_xor(psum, 32);
    l = l * scl + psum;
    m = mn;
    #pragma unroll
    for (int df = 0; df < 4; ++df) {
      o[df][0] *= scl; o[df][1] *= scl; o[df][2] *= scl; o[df][3] *= scl;
    }

    // --- P^T -> swizzled LDS (bf16), read back as B-frags ---
    #pragma unroll
    for (int jf = 0; jf < 4; ++jf) {
      unsigned d0 = (unsigned)pb[jf * 4 + 0] | ((unsigned)pb[jf * 4 + 1] << 16);
      unsigned d1 = (unsigned)pb[jf * 4 + 2] | ((unsigned)pb[jf * 4 + 3] << 16);
      *(uint2*)(pbase + ((pwb + jf * 32 + 8 * g) ^ swz)) = make_uint2(d0, d1);
    }
    asm volatile("s_waitcnt lgkmcnt(0)" ::: "memory");
    __builtin_amdgcn_sched_barrier(0);
    s16x8 pbf[2];
    #pragma unroll
    for (int kc = 0; kc < 2; ++kc)
      pbf[kc] = *(const s16x8*)(pbase + ((pwb + kc * 64 + 16 * g) ^ swz));

    // --- PV: O^T[d, i] += V^T frags x P^T ---
    #pragma unroll
    for (int df = 0; df < 4; ++df) {
      o[df] = __builtin_amdgcn_mfma_f32_16x16x32_bf16(va[df][0], pbf[0], o[df], 0, 0, 0);
      o[df] = __builtin_amdgcn_mfma_f32_16x16x32_bf16(va[df][1], pbf[1], o[df], 0, 0, 0);
    }
  }

  const float inv = 1.f / l;
  u16* op = Ovec + ((size_t)iglob * 2 + b) * 1024 + n * 64 + 4 * g;
  #pragma unroll
  for (int df = 0; df < 4; ++df) {
    unsigned d0 = (unsigned)f2b(o[df][0] * inv) | ((unsigned)f2b(o[df][1] * inv) << 16);
    unsigned d1 = (unsigned)f2b(o[df][2] * inv) | ((unsigned)f2b(o[df][3] * inv) << 16);
    *(uint2*)(op + df * 16) = make_uint2(d0, d1);
  }
}

// ---------------- LayerNorm over D=1024: out = LN(y + res [+ bias]) * gamma + beta -------
__global__ __launch_bounds__(256) void ln_kernel(const float* __restrict__ y,
                                                 const float* __restrict__ res,
                                                 const float* __restrict__ bias,
                                                 const float* __restrict__ gamma,
                                                 const float* __restrict__ beta,
                                                 float* __restrict__ outf,
                                                 u16* __restrict__ outb) {
  __shared__ float red[2][4];
  const int row = blockIdx.x;
  const int t = threadIdx.x;
  const size_t base = (size_t)row * 1024 + t * 4;
  float4 v = *(const float4*)(y + base);
  const float4 rv = *(const float4*)(res + base);
  v.x += rv.x; v.y += rv.y; v.z += rv.z; v.w += rv.w;
  if (bias) {
    const float4 bv = *(const float4*)(bias + t * 4);
    v.x += bv.x; v.y += bv.y; v.z += bv.z; v.w += bv.w;
  }
  float s = v.x + v.y + v.z + v.w;
  #pragma unroll
  for (int o = 32; o; o >>= 1) s += __shfl_xor(s, o);
  if ((t & 63) == 0) red[0][t >> 6] = s;
  __syncthreads();
  const float mean = (red[0][0] + red[0][1] + red[0][2] + red[0][3]) * (1.0f / 1024.0f);
  const float dx = v.x - mean, dy = v.y - mean, dz = v.z - mean, dw = v.w - mean;
  float s2 = dx * dx + dy * dy + dz * dz + dw * dw;
  #pragma unroll
  for (int o = 32; o; o >>= 1) s2 += __shfl_xor(s2, o);
  if ((t & 63) == 0) red[1][t >> 6] = s2;
  __syncthreads();
  const float var = (red[1][0] + red[1][1] + red[1][2] + red[1][3]) * (1.0f / 1024.0f);
  const float rstd = rsqrtf(var + 1e-12f);
  const float4 gv = *(const float4*)(gamma + t * 4);
  const float4 bv = *(const float4*)(beta + t * 4);
  float4 o4;
  o4.x = dx * rstd * gv.x + bv.x;
  o4.y = dy * rstd * gv.y + bv.y;
  o4.z = dz * rstd * gv.z + bv.z;
  o4.w = dw * rstd * gv.w + bv.w;
  if (outf) *(float4*)(outf + base) = o4;
  if (outb) *(ushort4*)(outb + base) = make_ushort4(f2b(o4.x), f2b(o4.y), f2b(o4.z), f2b(o4.w));
}

// ---------------- exact GELU + bias, f32 -> bf16; cols = 4096 ----------------
__global__ __launch_bounds__(256) void gelu_bias_kernel(const float* __restrict__ y,
                                                        const float* __restrict__ b,
                                                        u16* __restrict__ out, int total4) {
  int i = blockIdx.x * 256 + threadIdx.x;
  if (i >= total4) return;
  float4 v = ((const float4*)y)[i];
  const int c = (i * 4) & 4095;
  const float4 bv = *(const float4*)(b + c);
  v.x += bv.x; v.y += bv.y; v.z += bv.z; v.w += bv.w;
  const float k = 0.70710678118654752f;
  float gx = 0.5f * v.x * (1.f + erff(v.x * k));
  float gy = 0.5f * v.y * (1.f + erff(v.y * k));
  float gz = 0.5f * v.z * (1.f + erff(v.z * k));
  float gw = 0.5f * v.w * (1.f + erff(v.w * k));
  ((ushort4*)out)[i] = make_ushort4(f2b(gx), f2b(gy), f2b(gz), f2b(gw));
}

extern "C" void kernel_launch(void* const* d_in, const int* in_sizes, int n_in,
                              void* d_out, int out_size, void* d_ws, size_t ws_size,
                              hipStream_t stream) {
  (void)in_sizes; (void)n_in; (void)out_size; (void)ws_size;
  const float* h      = (const float*)d_in[0];
  const float* g      = (const float*)d_in[1];
  const float* r      = (const float*)d_in[2];
  const float* segmat = (const float*)d_in[5];
  const float* wq     = (const float*)d_in[6];
  const float* wk     = (const float*)d_in[7];
  const float* wv     = (const float*)d_in[8];
  const float* wo     = (const float*)d_in[9];
  const float* wr     = (const float*)d_in[10];
  const float* rwb    = (const float*)d_in[11];
  const float* rrb    = (const float*)d_in[12];
  const float* rsb    = (const float*)d_in[13];
  const float* sege   = (const float*)d_in[14];
  const float* lga    = (const float*)d_in[15];
  const float* lba    = (const float*)d_in[16];
  const float* fw1    = (const float*)d_in[17];
  const float* fb1    = (const float*)d_in[18];
  const float* fw2    = (const float*)d_in[19];
  const float* fb2    = (const float*)d_in[20];
  const float* lgf    = (const float*)d_in[21];
  const float* lbf    = (const float*)d_in[22];
  float* out = (float*)d_out;

  char* wp = (char*)d_ws;
  auto alloc = [&](size_t bytes) -> void* {
    void* p = (void*)wp;
    wp += (bytes + 1023) & ~((size_t)1023);
    return p;
  };
  u16* hb    = (u16*)alloc(2048ull * 1024 * 2);
  u16* gbuf  = (u16*)alloc(2048ull * 1024 * 2);
  u16* rb    = (u16*)alloc(4096ull * 1024 * 2);
  u16* wqT   = (u16*)alloc(1024ull * 1024 * 2);
  u16* wkT   = (u16*)alloc(1024ull * 1024 * 2);
  u16* wvT   = (u16*)alloc(1024ull * 1024 * 2);
  u16* wrT   = (u16*)alloc(1024ull * 1024 * 2);
  u16* woB   = (u16*)alloc(1024ull * 1024 * 2);
  u16* w1T   = (u16*)alloc(4096ull * 1024 * 2);
  u16* w2T   = (u16*)alloc(1024ull * 4096 * 2);
  float* kh   = (float*)alloc(2048ull * 1024 * 4);
  float* vh   = (float*)alloc(2048ull * 1024 * 4);
  float* kr   = (float*)alloc(4096ull * 1024 * 4);
  float* qh   = (float*)alloc(2048ull * 1024 * 4);
  float* qg   = (float*)alloc(2048ull * 1024 * 4);
  u16* khP   = (u16*)alloc(32ull * 1024 * 64 * 2);
  u16* krP   = (u16*)alloc(32ull * 2056 * 64 * 2);
  u16* qhP   = (u16*)alloc(32ull * 1024 * 64 * 2);
  u16* qgP   = (u16*)alloc(32ull * 1024 * 64 * 2);
  u16* vTb   = (u16*)alloc(32ull * 64 * 1024 * 2);
  float* tsegb = (float*)alloc(2048ull * 4);
  float* rwk2 = (float*)alloc(32ull * 1024 * 4);
  float* rrk2 = (float*)alloc(32ull * 2056 * 4);
  float* ef1h = (float*)alloc(1024ull * 2 * 16 * 2 * 4);
  float* ef1g = (float*)alloc(1024ull * 2 * 16 * 2 * 4);
  u16* vech  = (u16*)alloc(2048ull * 1024 * 2);
  u16* vecg  = (u16*)alloc(2048ull * 1024 * 2);
  float* tmp  = (float*)alloc(2048ull * 4096 * 4);
  float* x1f  = (float*)alloc(2048ull * 1024 * 4);
  u16* x1b   = (u16*)alloc(2048ull * 1024 * 2);
  u16* hid   = (u16*)alloc(2048ull * 4096 * 2);

  const dim3 blk(256);

  // --- convert activations / weights to bf16 (weights to B^T [N,K] layout) ---
  cvt_bf16_kernel<<<2048, blk, 0, stream>>>(h, hb, 524288);
  cvt_bf16_kernel<<<2048, blk, 0, stream>>>(g, gbuf, 524288);
  cvt_bf16_kernel<<<4096, blk, 0, stream>>>(r, rb, 1048576);
  cvt_bf16_kernel<<<1024, blk, 0, stream>>>(wo, woB, 262144);
  transpose_cvt_kernel<<<dim3(32, 32), blk, 0, stream>>>(wq, wqT, 1024, 1024);
  transpose_cvt_kernel<<<dim3(32, 32), blk, 0, stream>>>(wk, wkT, 1024, 1024);
  transpose_cvt_kernel<<<dim3(32, 32), blk, 0, stream>>>(wv, wvT, 1024, 1024);
  transpose_cvt_kernel<<<dim3(32, 32), blk, 0, stream>>>(wr, wrT, 1024, 1024);
  transpose_cvt_kernel<<<dim3(128, 32), blk, 0, stream>>>(fw1, w1T, 1024, 4096);
  transpose_cvt_kernel<<<dim3(32, 128), blk, 0, stream>>>(fw2, w2T, 4096, 1024);

  // --- shared projections (64-row tiles -> 256/512-block grids) ---
  gemm_bt64<<<dim3(8, 32), blk, 0, stream>>>(hb, wkT, kh, 2048, 1024, 1024);
  gemm_bt64<<<dim3(8, 32), blk, 0, stream>>>(hb, wvT, vh, 2048, 1024, 1024);
  gemm_bt64<<<dim3(8, 64), blk, 0, stream>>>(rb, wrT, kr, 4096, 1024, 1024);
  gemm_bt64<<<dim3(8, 32), blk, 0, stream>>>(hb, wqT, qh, 2048, 1024, 1024);
  gemm_bt64<<<dim3(8, 32), blk, 0, stream>>>(gbuf, wqT, qg, 2048, 1024, 1024);

  // --- attention precomputes ---
  tseg_kernel<<<8, blk, 0, stream>>>(segmat, tsegb);
  headperm_kernel<<<dim3(64, 32), blk, 0, stream>>>(kh, khP, 1024, 1024);
  headperm_kernel<<<dim3(129, 32), blk, 0, stream>>>(kr, krP, 2048, 2056);
  headperm_kernel<<<dim3(64, 32), blk, 0, stream>>>(qh, qhP, 1024, 1024);
  headperm_kernel<<<dim3(64, 32), blk, 0, stream>>>(qg, qgP, 1024, 1024);
  vtrans_kernel<<<dim3(16, 32), blk, 0, stream>>>(vh, vTb);
  rowdot_kernel<<<8192, blk, 0, stream>>>(kh, rwb, rwk2, 32768, 1024, 0);
  rowdot_kernel<<<16384, blk, 0, stream>>>(kr, rrb, rrk2, 65536, 2056, 3);
  ef1_kernel<<<8192, blk, 0, stream>>>(qh, rsb, sege, ef1h, 32768);
  ef1_kernel<<<8192, blk, 0, stream>>>(qg, rsb, sege, ef1g, 32768);

  // --- per-stream: attention -> wo -> LN -> FFN -> LN ---
  for (int s = 0; s < 2; ++s) {
    const u16* qPs    = s ? qgP : qhP;
    const float* ef1s = s ? ef1g : ef1h;
    const float* res  = s ? g : h;
    u16* vec          = s ? vecg : vech;
    float* outp       = out + (size_t)s * 2048 * 1024;

    attn_mfma_kernel<<<dim3(16, 32), blk, 0, stream>>>(qPs, khP, krP, vTb, rwk2, rrk2,
                                                       ef1s, tsegb, vec, s);
    gemm_bt64<<<dim3(8, 32), blk, 0, stream>>>(vec, woB, tmp, 2048, 1024, 1024);
    ln_kernel<<<2048, blk, 0, stream>>>(tmp, res, nullptr, lga, lba, x1f, x1b);
    gemm_bt<<<dim3(32, 16), blk, 0, stream>>>(x1b, w1T, tmp, 2048, 4096, 1024);
    gelu_bias_kernel<<<8192, blk, 0, stream>>>(tmp, fb1, hid, 2097152);
    gemm_bt64<<<dim3(8, 32), blk, 0, stream>>>(hid, w2T, tmp, 2048, 1024, 4096);
    ln_kernel<<<2048, blk, 0, stream>>>(tmp, x1f, fb2, lgf, lbf, outp, nullptr);
  }
}

// Round 7
// 815.425 us; speedup vs baseline: 1.0518x; 1.0518x over previous
//
#include <hip/hip_runtime.h>
#include <cstdint>
#include <cstddef>

using u16 = unsigned short;

typedef __attribute__((ext_vector_type(4))) int   i32x4;
typedef __attribute__((ext_vector_type(4))) float f32x4;
typedef __attribute__((ext_vector_type(8))) short s16x8;

__device__ __forceinline__ u16 f2b(float f) {
  union { float f; unsigned u; } x; x.f = f;
  unsigned r = x.u + 0x7fffu + ((x.u >> 16) & 1u);   // RNE
  return (u16)(r >> 16);
}

// ---------------- elementwise cvt f32 -> bf16 (float4 vectorized) ----------------
__global__ __launch_bounds__(256) void cvt_bf16_kernel(const float* __restrict__ src,
                                                       u16* __restrict__ dst, int n4) {
  int i = blockIdx.x * 256 + threadIdx.x;
  if (i >= n4) return;
  float4 v = ((const float4*)src)[i];
  ((ushort4*)dst)[i] = make_ushort4(f2b(v.x), f2b(v.y), f2b(v.z), f2b(v.w));
}

// ---------------- transpose + cvt: dst[c][r] = (bf16)src[r][c] ----------------
__global__ __launch_bounds__(256) void transpose_cvt_kernel(const float* __restrict__ src,
                                                            u16* __restrict__ dst,
                                                            int R, int C) {
  __shared__ float t[32][33];
  const int tx = threadIdx.x & 31, ty = threadIdx.x >> 5;
  const int c0 = blockIdx.x * 32, r0 = blockIdx.y * 32;
  #pragma unroll
  for (int k = 0; k < 32; k += 8)
    t[ty + k][tx] = src[(size_t)(r0 + ty + k) * C + c0 + tx];
  __syncthreads();
  #pragma unroll
  for (int k = 0; k < 32; k += 8)
    dst[(size_t)(c0 + ty + k) * R + r0 + tx] = f2b(t[tx][ty + k]);
}

// ---------------- bf16 MFMA GEMM 128x128 tile (plain f32 C out) ----------------
__global__ __launch_bounds__(256) void gemm_bt(const u16* __restrict__ A,
                                               const u16* __restrict__ B,
                                               float* __restrict__ C,
                                               int M, int N, int K) {
  (void)M;
  __shared__ __align__(16) u16 As[128 * 32];
  __shared__ __align__(16) u16 Bs[128 * 32];
  const int tid  = threadIdx.x;
  const int wid  = tid >> 6;
  const int lane = tid & 63;
  const int m0 = blockIdx.y * 128;
  const int n0 = blockIdx.x * 128;
  const int wm = (wid >> 1) * 64;
  const int wn = (wid & 1) * 64;

  const int srow = wid * 32 + (lane >> 2);
  const int scol = (lane & 3) * 8;
  const int fr = lane & 15;
  const int fk = (lane >> 4) * 8;

  f32x4 acc[4][4] = {};

  for (int k0 = 0; k0 < K; k0 += 32) {
    const u16* ga0 = A + (size_t)(m0 + srow) * K + k0 + scol;
    const u16* ga1 = ga0 + (size_t)16 * K;
    const u16* gb0 = B + (size_t)(n0 + srow) * K + k0 + scol;
    const u16* gb1 = gb0 + (size_t)16 * K;
    __builtin_amdgcn_global_load_lds((const __attribute__((address_space(1))) void*)ga0,
                                     (__attribute__((address_space(3))) void*)(As + wid * 1024), 16, 0, 0);
    __builtin_amdgcn_global_load_lds((const __attribute__((address_space(1))) void*)ga1,
                                     (__attribute__((address_space(3))) void*)(As + wid * 1024 + 512), 16, 0, 0);
    __builtin_amdgcn_global_load_lds((const __attribute__((address_space(1))) void*)gb0,
                                     (__attribute__((address_space(3))) void*)(Bs + wid * 1024), 16, 0, 0);
    __builtin_amdgcn_global_load_lds((const __attribute__((address_space(1))) void*)gb1,
                                     (__attribute__((address_space(3))) void*)(Bs + wid * 1024 + 512), 16, 0, 0);
    __syncthreads();

    i32x4 av[4], bv[4];
    #pragma unroll
    for (int i = 0; i < 4; ++i)
      av[i] = *(const i32x4*)(As + (wm + i * 16 + fr) * 32 + fk);
    #pragma unroll
    for (int j = 0; j < 4; ++j)
      bv[j] = *(const i32x4*)(Bs + (wn + j * 16 + fr) * 32 + fk);

    #pragma unroll
    for (int i = 0; i < 4; ++i) {
      #pragma unroll
      for (int j = 0; j < 4; ++j) {
        asm volatile("v_mfma_f32_16x16x32_bf16 %0, %1, %2, %0"
                     : "+v"(acc[i][j]) : "v"(av[i]), "v"(bv[j]));
      }
    }
    __syncthreads();
  }
  asm volatile("s_nop 7\ns_nop 7\ns_nop 7" : : :);

  const int er = (lane >> 4) * 4;
  #pragma unroll
  for (int i = 0; i < 4; ++i) {
    #pragma unroll
    for (int j = 0; j < 4; ++j) {
      const int r0 = m0 + wm + i * 16 + er;
      const int c  = n0 + wn + j * 16 + fr;
      #pragma unroll
      for (int r = 0; r < 4; ++r)
        C[(size_t)(r0 + r) * N + c] = acc[i][j][r];
    }
  }
}

// ---------------- bf16 MFMA GEMM 128x128 tile + bias + exact GELU -> bf16 out ----------
__global__ __launch_bounds__(256) void gemm_bt_gelu(const u16* __restrict__ A,
                                                    const u16* __restrict__ B,
                                                    const float* __restrict__ bias,
                                                    u16* __restrict__ Cb,
                                                    int M, int N, int K) {
  (void)M;
  __shared__ __align__(16) u16 As[128 * 32];
  __shared__ __align__(16) u16 Bs[128 * 32];
  const int tid  = threadIdx.x;
  const int wid  = tid >> 6;
  const int lane = tid & 63;
  const int m0 = blockIdx.y * 128;
  const int n0 = blockIdx.x * 128;
  const int wm = (wid >> 1) * 64;
  const int wn = (wid & 1) * 64;

  const int srow = wid * 32 + (lane >> 2);
  const int scol = (lane & 3) * 8;
  const int fr = lane & 15;
  const int fk = (lane >> 4) * 8;

  f32x4 acc[4][4] = {};

  for (int k0 = 0; k0 < K; k0 += 32) {
    const u16* ga0 = A + (size_t)(m0 + srow) * K + k0 + scol;
    const u16* ga1 = ga0 + (size_t)16 * K;
    const u16* gb0 = B + (size_t)(n0 + srow) * K + k0 + scol;
    const u16* gb1 = gb0 + (size_t)16 * K;
    __builtin_amdgcn_global_load_lds((const __attribute__((address_space(1))) void*)ga0,
                                     (__attribute__((address_space(3))) void*)(As + wid * 1024), 16, 0, 0);
    __builtin_amdgcn_global_load_lds((const __attribute__((address_space(1))) void*)ga1,
                                     (__attribute__((address_space(3))) void*)(As + wid * 1024 + 512), 16, 0, 0);
    __builtin_amdgcn_global_load_lds((const __attribute__((address_space(1))) void*)gb0,
                                     (__attribute__((address_space(3))) void*)(Bs + wid * 1024), 16, 0, 0);
    __builtin_amdgcn_global_load_lds((const __attribute__((address_space(1))) void*)gb1,
                                     (__attribute__((address_space(3))) void*)(Bs + wid * 1024 + 512), 16, 0, 0);
    __syncthreads();

    i32x4 av[4], bv[4];
    #pragma unroll
    for (int i = 0; i < 4; ++i)
      av[i] = *(const i32x4*)(As + (wm + i * 16 + fr) * 32 + fk);
    #pragma unroll
    for (int j = 0; j < 4; ++j)
      bv[j] = *(const i32x4*)(Bs + (wn + j * 16 + fr) * 32 + fk);

    #pragma unroll
    for (int i = 0; i < 4; ++i) {
      #pragma unroll
      for (int j = 0; j < 4; ++j) {
        asm volatile("v_mfma_f32_16x16x32_bf16 %0, %1, %2, %0"
                     : "+v"(acc[i][j]) : "v"(av[i]), "v"(bv[j]));
      }
    }
    __syncthreads();
  }
  asm volatile("s_nop 7\ns_nop 7\ns_nop 7" : : :);

  const int er = (lane >> 4) * 4;
  const float kk = 0.70710678118654752f;
  #pragma unroll
  for (int i = 0; i < 4; ++i) {
    #pragma unroll
    for (int j = 0; j < 4; ++j) {
      const int r0 = m0 + wm + i * 16 + er;
      const int c  = n0 + wn + j * 16 + fr;
      const float bv = bias[c];
      #pragma unroll
      for (int r = 0; r < 4; ++r) {
        const float v = acc[i][j][r] + bv;
        const float gel = 0.5f * v * (1.f + erff(v * kk));
        Cb[(size_t)(r0 + r) * N + c] = f2b(gel);
      }
    }
  }
}

// ---------------- bf16 MFMA GEMM 64x128 tile (for N=1024 shapes: 2x the grid) ----------
__global__ __launch_bounds__(256) void gemm_bt64(const u16* __restrict__ A,
                                                 const u16* __restrict__ B,
                                                 float* __restrict__ C,
                                                 int M, int N, int K) {
  (void)M;
  __shared__ __align__(16) u16 As[64 * 32];
  __shared__ __align__(16) u16 Bs[128 * 32];
  const int tid  = threadIdx.x;
  const int wid  = tid >> 6;
  const int lane = tid & 63;
  const int m0 = blockIdx.y * 64;
  const int n0 = blockIdx.x * 128;
  const int wm = (wid >> 1) * 32;
  const int wn = (wid & 1) * 64;

  const int srowA = wid * 16 + (lane >> 2);
  const int srowB = wid * 32 + (lane >> 2);
  const int scol = (lane & 3) * 8;
  const int fr = lane & 15;
  const int fk = (lane >> 4) * 8;

  f32x4 acc[2][4] = {};

  for (int k0 = 0; k0 < K; k0 += 32) {
    const u16* ga  = A + (size_t)(m0 + srowA) * K + k0 + scol;
    const u16* gb0 = B + (size_t)(n0 + srowB) * K + k0 + scol;
    const u16* gb1 = gb0 + (size_t)16 * K;
    __builtin_amdgcn_global_load_lds((const __attribute__((address_space(1))) void*)ga,
                                     (__attribute__((address_space(3))) void*)(As + wid * 512), 16, 0, 0);
    __builtin_amdgcn_global_load_lds((const __attribute__((address_space(1))) void*)gb0,
                                     (__attribute__((address_space(3))) void*)(Bs + wid * 1024), 16, 0, 0);
    __builtin_amdgcn_global_load_lds((const __attribute__((address_space(1))) void*)gb1,
                                     (__attribute__((address_space(3))) void*)(Bs + wid * 1024 + 512), 16, 0, 0);
    __syncthreads();

    i32x4 av[2], bv[4];
    #pragma unroll
    for (int i = 0; i < 2; ++i)
      av[i] = *(const i32x4*)(As + (wm + i * 16 + fr) * 32 + fk);
    #pragma unroll
    for (int j = 0; j < 4; ++j)
      bv[j] = *(const i32x4*)(Bs + (wn + j * 16 + fr) * 32 + fk);

    #pragma unroll
    for (int i = 0; i < 2; ++i) {
      #pragma unroll
      for (int j = 0; j < 4; ++j) {
        asm volatile("v_mfma_f32_16x16x32_bf16 %0, %1, %2, %0"
                     : "+v"(acc[i][j]) : "v"(av[i]), "v"(bv[j]));
      }
    }
    __syncthreads();
  }
  asm volatile("s_nop 7\ns_nop 7\ns_nop 7" : : :);

  const int er = (lane >> 4) * 4;
  #pragma unroll
  for (int i = 0; i < 2; ++i) {
    #pragma unroll
    for (int j = 0; j < 4; ++j) {
      const int r0 = m0 + wm + i * 16 + er;
      const int c  = n0 + wn + j * 16 + fr;
      #pragma unroll
      for (int r = 0; r < 4; ++r)
        C[(size_t)(r0 + r) * N + c] = acc[i][j][r];
    }
  }
}

// ---------------- per-head permute: dst[bn][row][64] bf16 from src[(row*2+b)*1024+n*64+d] -
__global__ __launch_bounds__(256) void headperm_kernel(const float* __restrict__ src,
                                                       u16* __restrict__ dst,
                                                       int Rsrc, int Rdst) {
  const int bn = blockIdx.y, b = bn >> 4, n = bn & 15;
  const int row = blockIdx.x * 16 + (threadIdx.x >> 4);
  const int d4 = (threadIdx.x & 15) * 4;
  if (row >= Rdst) return;
  u16* dp = dst + ((size_t)bn * Rdst + row) * 64 + d4;
  if (row < Rsrc) {
    float4 v = *(const float4*)(src + ((size_t)row * 2 + b) * 1024 + n * 64 + d4);
    *(ushort4*)dp = make_ushort4(f2b(v.x), f2b(v.y), f2b(v.z), f2b(v.w));
  } else {
    *(ushort4*)dp = make_ushort4(0, 0, 0, 0);
  }
}

// ---------------- rowdot: out[bn*ostride + ooff + row] = bias[n].mat_row --------
__global__ __launch_bounds__(256) void rowdot_kernel(const float* __restrict__ mat,
                                                     const float* __restrict__ bias,
                                                     float* __restrict__ out, int tasks,
                                                     int ostride, int ooff) {
  const int task = blockIdx.x * 4 + (threadIdx.x >> 6);
  const int lane = threadIdx.x & 63;
  if (task >= tasks) return;
  const int jb = task >> 4, n = task & 15;
  float v = mat[(size_t)jb * 1024 + n * 64 + lane] * bias[n * 64 + lane];
  #pragma unroll
  for (int o = 32; o; o >>= 1) v += __shfl_xor(v, o);
  if (lane == 0) out[(size_t)((jb & 1) * 16 + n) * ostride + ooff + (jb >> 1)] = v;
}

// ---------------- ef1: out[task*2+s] = sum_d (q[ib,n,d] + rsb[n,d]) * seg[s,n,d] ----------
__global__ __launch_bounds__(256) void ef1_kernel(const float* __restrict__ q,
                                                  const float* __restrict__ rsb,
                                                  const float* __restrict__ seg,
                                                  float* __restrict__ out, int tasks) {
  const int task = blockIdx.x * 4 + (threadIdx.x >> 6);
  const int lane = threadIdx.x & 63;
  if (task >= tasks) return;
  const int ib = task >> 4, n = task & 15;
  const float qv = q[(size_t)ib * 1024 + n * 64 + lane] + rsb[n * 64 + lane];
  float a = qv * seg[n * 64 + lane];
  float c = qv * seg[1024 + n * 64 + lane];
  #pragma unroll
  for (int o = 32; o; o >>= 1) { a += __shfl_xor(a, o); c += __shfl_xor(c, o); }
  if (lane == 0) { out[(size_t)task * 2] = a; out[(size_t)task * 2 + 1] = c; }
}

// ---------------- tseg: t[b*1024 + j] = seg_mat[0, j, b, 1] ----
__global__ __launch_bounds__(256) void tseg_kernel(const float* __restrict__ segmat,
                                                   float* __restrict__ t) {
  const int idx = blockIdx.x * 256 + threadIdx.x;
  if (idx >= 2048) return;
  const int b = idx >> 10, j = idx & 1023;
  t[idx] = segmat[((size_t)j * 2 + b) * 2 + 1];
}

// ---------------- V transpose: vt[(bn*64+d)*1024 + j] = bf16(vh[(j*2+b)*1024 + n*64 + d]) -
__global__ __launch_bounds__(256) void vtrans_kernel(const float* __restrict__ vh,
                                                     u16* __restrict__ vt) {
  __shared__ float t[64][65];
  const int bn = blockIdx.y, b = bn >> 4, n = bn & 15;
  const int j0 = blockIdx.x * 64;
  const int r = threadIdx.x >> 2, c16 = (threadIdx.x & 3) * 16;
  const float* src = vh + ((size_t)(j0 + r) * 2 + b) * 1024 + n * 64 + c16;
  #pragma unroll
  for (int k = 0; k < 16; k += 4)
    *(float4*)&t[r][c16 + k] = *(const float4*)(src + k);
  __syncthreads();
  u16 v[16];
  #pragma unroll
  for (int k = 0; k < 16; ++k) v[k] = f2b(t[c16 + k][r]);
  u16* dst = vt + ((size_t)bn * 64 + r) * 1024 + j0 + c16;
  #pragma unroll
  for (int k = 0; k < 16; k += 8)
    *(uint4*)(dst + k) = *(const uint4*)&v[k];
}

// ---------------- MFMA relative attention, flash-decode j-split ------
// grid (16 it64 x 4 jc, 32 bn), 256 threads (4 waves). Wave w owns rows it64*64+w*16+il.
// Each block does <=4 j-tiles [4*jc, min(4*jc+4, NT)); partial (unnorm O, m, l) to PO/PML.
__global__ __launch_bounds__(256) void attn_mfma_kernel(
    const u16* __restrict__ QP, const u16* __restrict__ KP,
    const u16* __restrict__ KrP, const u16* __restrict__ Vtb,
    const float* __restrict__ rwk2, const float* __restrict__ rrk2,
    const float* __restrict__ ef1, const float* __restrict__ tsegp,
    float* __restrict__ PO, float* __restrict__ PML, int isG) {
  __shared__ __align__(16) float bdts[4][16][84];   // per-wave band (80 rows used)
  __shared__ __align__(16) u16   ps[4][1024];       // per-wave 16x64 bf16 P^T, swizzled

  const int it64 = blockIdx.x >> 2, jc = blockIdx.x & 3;
  const int bn = blockIdx.y, b = bn >> 4, n = bn & 15;
  const int NTf = (isG && it64 == 0) ? 16 : (it64 + 1);
  if (jc * 4 >= NTf) return;                        // empty chunk
  const int jt0 = jc * 4;
  const int jt1 = (jt0 + 4 < NTf) ? (jt0 + 4) : NTf;

  const int w = threadIdx.x >> 6, lane = threadIdx.x & 63;
  const int il = lane & 15, g = lane >> 4;
  const int i0 = it64 * 64 + w * 16;                // this wave's 16-row base
  const int iglob = i0 + il;

  // Q as B-frags (col = q-row, k = d), bf16 per-head layout
  s16x8 qf[2];
  {
    const u16* qrow = QP + ((size_t)bn * 1024 + iglob) * 64;
    qf[0] = *(const s16x8*)(qrow + g * 8);
    qf[1] = *(const s16x8*)(qrow + 32 + g * 8);
  }
  const float2 efv = *(const float2*)(ef1 + (((size_t)iglob * 2 + b) * 16 + n) * 2);
  const float e0 = efv.x, ed = efv.y - efv.x;
  const float ti = tsegp[b * 1024 + iglob];

  f32x4 o[4] = {};
  float m = -1e30f, l = 0.f;

  const u16* kbase  = KP  + (size_t)bn * 1024 * 64 + g * 8;
  const u16* krbase = KrP + (size_t)bn * 2056 * 64 + g * 8;
  const u16* vbase  = Vtb + ((size_t)bn * 64 + il) * 1024 + g * 8;
  const float* rwkp = rwk2 + (size_t)bn * 1024;
  const float* rrkp = rrk2 + (size_t)bn * 2056 + 3;
  const float* tjp  = tsegp + b * 1024;
  char* pbase = (char*)&ps[w][0];
  const int pwb = il * 128;
  const int swz = (il & 7) << 4;

  for (int jt = jt0; jt < jt1; ++jt) {
    const int j0 = jt * 64;
    const int base = 1009 + j0 - i0;   // kr row of band idx 0; band idx = jl - il + 15 in [0,78]

    // --- AC: S^T[j, i] ---
    f32x4 sT[4] = {};
    #pragma unroll
    for (int jf = 0; jf < 4; ++jf) {
      const u16* kp = kbase + (size_t)(j0 + jf * 16 + il) * 64;
      s16x8 k0 = *(const s16x8*)kp;
      s16x8 k1 = *(const s16x8*)(kp + 32);
      sT[jf] = __builtin_amdgcn_mfma_f32_16x16x32_bf16(k0, qf[0], sT[jf], 0, 0, 0);
      sT[jf] = __builtin_amdgcn_mfma_f32_16x16x32_bf16(k1, qf[1], sT[jf], 0, 0, 0);
    }

    // --- V frags early (overlap with BD + softmax) ---
    s16x8 va[4][2];
    #pragma unroll
    for (int df = 0; df < 4; ++df) {
      const u16* vp = vbase + (size_t)df * 16384 + j0;
      va[df][0] = *(const s16x8*)vp;
      va[df][1] = *(const s16x8*)(vp + 32);
    }

    // --- BD band (80 kr rows, 5 frags) + rrk prefold -> LDS ---
    #pragma unroll
    for (int jf5 = 0; jf5 < 5; ++jf5) {
      const u16* kp = krbase + (size_t)(base + jf5 * 16 + il) * 64;
      s16x8 k0 = *(const s16x8*)kp;
      s16x8 k1 = *(const s16x8*)(kp + 32);
      f32x4 bdt = {};
      bdt = __builtin_amdgcn_mfma_f32_16x16x32_bf16(k0, qf[0], bdt, 0, 0, 0);
      bdt = __builtin_amdgcn_mfma_f32_16x16x32_bf16(k1, qf[1], bdt, 0, 0, 0);
      const float4 rr = *(const float4*)(rrkp + base + jf5 * 16 + 4 * g);
      bdt[0] += rr.x; bdt[1] += rr.y; bdt[2] += rr.z; bdt[3] += rr.w;
      *(f32x4*)&bdts[w][il][jf5 * 16 + 4 * g] = bdt;
    }

    // --- assemble scores (rel-shift gather + rwk + ef + analytic mask) ---
    float sc[4][4];
    float tmax = -INFINITY;
    #pragma unroll
    for (int jf = 0; jf < 4; ++jf) {
      const float4 rw = *(const float4*)(rwkp + j0 + jf * 16 + 4 * g);
      const float4 tj = *(const float4*)(tjp + j0 + jf * 16 + 4 * g);
      #pragma unroll
      for (int r = 0; r < 4; ++r) {
        const int jl = jf * 16 + 4 * g + r;
        const float bd = bdts[w][il][jl - il + 15];
        const float tjv = r == 0 ? tj.x : r == 1 ? tj.y : r == 2 ? tj.z : tj.w;
        const float rwv = r == 0 ? rw.x : r == 1 ? rw.y : r == 2 ? rw.z : rw.w;
        float s = (sT[jf][r] + bd + rwv + e0 + fabsf(ti - tjv) * ed) * 0.125f;
        const int j = j0 + jl;
        const bool masked = isG ? (j >= iglob) : (j > iglob);
        s = masked ? -1e30f : s;
        sc[jf][r] = s;
        tmax = fmaxf(tmax, s);
      }
    }
    tmax = fmaxf(tmax, __shfl_xor(tmax, 16));
    tmax = fmaxf(tmax, __shfl_xor(tmax, 32));
    const float mn = fmaxf(m, tmax);
    const float scl = __expf(m - mn);
    float psum = 0.f;
    u16 pb[16];
    #pragma unroll
    for (int jf = 0; jf < 4; ++jf) {
      #pragma unroll
      for (int r = 0; r < 4; ++r) {
        const float p = __expf(sc[jf][r] - mn);
        psum += p;
        pb[jf * 4 + r] = f2b(p);
      }
    }
    psum += __shfl_xor(psum, 16);
    psum += __shfl_xor(psum, 32);
    l = l * scl + psum;
    m = mn;
    #pragma unroll
    for (int df = 0; df < 4; ++df) {
      o[df][0] *= scl; o[df][1] *= scl; o[df][2] *= scl; o[df][3] *= scl;
    }

    // --- P^T -> swizzled LDS (bf16), read back as B-frags (per-wave, compiler waits) ---
    #pragma unroll
    for (int jf = 0; jf < 4; ++jf) {
      unsigned d0 = (unsigned)pb[jf * 4 + 0] | ((unsigned)pb[jf * 4 + 1] << 16);
      unsigned d1 = (unsigned)pb[jf * 4 + 2] | ((unsigned)pb[jf * 4 + 3] << 16);
      *(uint2*)(pbase + ((pwb + jf * 32 + 8 * g) ^ swz)) = make_uint2(d0, d1);
    }
    s16x8 pbf[2];
    #pragma unroll
    for (int kc = 0; kc < 2; ++kc)
      pbf[kc] = *(const s16x8*)(pbase + ((pwb + kc * 64 + 16 * g) ^ swz));

    // --- PV: O^T[d, i] += V^T frags x P^T ---
    #pragma unroll
    for (int df = 0; df < 4; ++df) {
      o[df] = __builtin_amdgcn_mfma_f32_16x16x32_bf16(va[df][0], pbf[0], o[df], 0, 0, 0);
      o[df] = __builtin_amdgcn_mfma_f32_16x16x32_bf16(va[df][1], pbf[1], o[df], 0, 0, 0);
    }
  }

  // --- write partial (unnormalized O, m, l) ---
  const int chunk = (bn * 16 + it64) * 4 + jc;
  const int row = w * 16 + il;
  if (g == 0) {
    float2* pml = (float2*)(PML + ((size_t)chunk * 64 + row) * 2);
    *pml = make_float2(m, l);
  }
  float* pop = PO + ((size_t)chunk * 64 + row) * 64 + 4 * g;
  #pragma unroll
  for (int df = 0; df < 4; ++df)
    *(f32x4*)(pop + df * 16) = o[df];
}

// ---------------- combine partials: out bf16 = (sum_p e^{m_p-m*} O_p) / (sum e^{m_p-m*} l_p)
__global__ __launch_bounds__(256) void attn_combine_kernel(
    const float* __restrict__ PO, const float* __restrict__ PML,
    u16* __restrict__ Ovec, int isG) {
  const int it64 = blockIdx.x, bn = blockIdx.y, b = bn >> 4, n = bn & 15;
  const int NTf = (isG && it64 == 0) ? 16 : (it64 + 1);
  const int P = (NTf + 3) >> 2;
  const int r = threadIdx.x >> 2, dg = threadIdx.x & 3;
  const int bc = (bn * 16 + it64) * 4;

  float mm = -INFINITY;
  for (int p = 0; p < P; ++p)
    mm = fmaxf(mm, PML[((size_t)(bc + p) * 64 + r) * 2]);

  float l = 0.f;
  float acc[16];
  #pragma unroll
  for (int d = 0; d < 16; ++d) acc[d] = 0.f;
  for (int p = 0; p < P; ++p) {
    const float2 ml = *(const float2*)(PML + ((size_t)(bc + p) * 64 + r) * 2);
    const float s = __expf(ml.x - mm);
    l += s * ml.y;
    const float* pop = PO + ((size_t)(bc + p) * 64 + r) * 64 + dg * 16;
    #pragma unroll
    for (int d = 0; d < 16; d += 4) {
      float4 v = *(const float4*)(pop + d);
      acc[d] += s * v.x; acc[d + 1] += s * v.y; acc[d + 2] += s * v.z; acc[d + 3] += s * v.w;
    }
  }
  const float inv = 1.f / l;
  const int iglob = it64 * 64 + r;
  u16* op = Ovec + ((size_t)iglob * 2 + b) * 1024 + n * 64 + dg * 16;
  #pragma unroll
  for (int d = 0; d < 16; d += 4)
    *(ushort4*)(op + d) = make_ushort4(f2b(acc[d] * inv), f2b(acc[d + 1] * inv),
                                       f2b(acc[d + 2] * inv), f2b(acc[d + 3] * inv));
}

// ---------------- LayerNorm over D=1024: out = LN(y + res [+ bias]) * gamma + beta -------
__global__ __launch_bounds__(256) void ln_kernel(const float* __restrict__ y,
                                                 const float* __restrict__ res,
                                                 const float* __restrict__ bias,
                                                 const float* __restrict__ gamma,
                                                 const float* __restrict__ beta,
                                                 float* __restrict__ outf,
                                                 u16* __restrict__ outb) {
  __shared__ float red[2][4];
  const int row = blockIdx.x;
  const int t = threadIdx.x;
  const size_t base = (size_t)row * 1024 + t * 4;
  float4 v = *(const float4*)(y + base);
  const float4 rv = *(const float4*)(res + base);
  v.x += rv.x; v.y += rv.y; v.z += rv.z; v.w += rv.w;
  if (bias) {
    const float4 bv = *(const float4*)(bias + t * 4);
    v.x += bv.x; v.y += bv.y; v.z += bv.z; v.w += bv.w;
  }
  float s = v.x + v.y + v.z + v.w;
  #pragma unroll
  for (int o = 32; o; o >>= 1) s += __shfl_xor(s, o);
  if ((t & 63) == 0) red[0][t >> 6] = s;
  __syncthreads();
  const float mean = (red[0][0] + red[0][1] + red[0][2] + red[0][3]) * (1.0f / 1024.0f);
  const float dx = v.x - mean, dy = v.y - mean, dz = v.z - mean, dw = v.w - mean;
  float s2 = dx * dx + dy * dy + dz * dz + dw * dw;
  #pragma unroll
  for (int o = 32; o; o >>= 1) s2 += __shfl_xor(s2, o);
  if ((t & 63) == 0) red[1][t >> 6] = s2;
  __syncthreads();
  const float var = (red[1][0] + red[1][1] + red[1][2] + red[1][3]) * (1.0f / 1024.0f);
  const float rstd = rsqrtf(var + 1e-12f);
  const float4 gv = *(const float4*)(gamma + t * 4);
  const float4 bv = *(const float4*)(beta + t * 4);
  float4 o4;
  o4.x = dx * rstd * gv.x + bv.x;
  o4.y = dy * rstd * gv.y + bv.y;
  o4.z = dz * rstd * gv.z + bv.z;
  o4.w = dw * rstd * gv.w + bv.w;
  if (outf) *(float4*)(outf + base) = o4;
  if (outb) *(ushort4*)(outb + base) = make_ushort4(f2b(o4.x), f2b(o4.y), f2b(o4.z), f2b(o4.w));
}

extern "C" void kernel_launch(void* const* d_in, const int* in_sizes, int n_in,
                              void* d_out, int out_size, void* d_ws, size_t ws_size,
                              hipStream_t stream) {
  (void)in_sizes; (void)n_in; (void)out_size; (void)ws_size;
  const float* h      = (const float*)d_in[0];
  const float* g      = (const float*)d_in[1];
  const float* r      = (const float*)d_in[2];
  const float* segmat = (const float*)d_in[5];
  const float* wq     = (const float*)d_in[6];
  const float* wk     = (const float*)d_in[7];
  const float* wv     = (const float*)d_in[8];
  const float* wo     = (const float*)d_in[9];
  const float* wr     = (const float*)d_in[10];
  const float* rwb    = (const float*)d_in[11];
  const float* rrb    = (const float*)d_in[12];
  const float* rsb    = (const float*)d_in[13];
  const float* sege   = (const float*)d_in[14];
  const float* lga    = (const float*)d_in[15];
  const float* lba    = (const float*)d_in[16];
  const float* fw1    = (const float*)d_in[17];
  const float* fb1    = (const float*)d_in[18];
  const float* fw2    = (const float*)d_in[19];
  const float* fb2    = (const float*)d_in[20];
  const float* lgf    = (const float*)d_in[21];
  const float* lbf    = (const float*)d_in[22];
  float* out = (float*)d_out;

  char* wp = (char*)d_ws;
  auto alloc = [&](size_t bytes) -> void* {
    void* p = (void*)wp;
    wp += (bytes + 1023) & ~((size_t)1023);
    return p;
  };
  u16* hb    = (u16*)alloc(2048ull * 1024 * 2);
  u16* gbuf  = (u16*)alloc(2048ull * 1024 * 2);
  u16* rb    = (u16*)alloc(4096ull * 1024 * 2);
  u16* wqT   = (u16*)alloc(1024ull * 1024 * 2);
  u16* wkT   = (u16*)alloc(1024ull * 1024 * 2);
  u16* wvT   = (u16*)alloc(1024ull * 1024 * 2);
  u16* wrT   = (u16*)alloc(1024ull * 1024 * 2);
  u16* woB   = (u16*)alloc(1024ull * 1024 * 2);
  u16* w1T   = (u16*)alloc(4096ull * 1024 * 2);
  u16* w2T   = (u16*)alloc(1024ull * 4096 * 2);
  float* kh   = (float*)alloc(2048ull * 1024 * 4);
  float* vh   = (float*)alloc(2048ull * 1024 * 4);
  float* kr   = (float*)alloc(4096ull * 1024 * 4);
  float* qh   = (float*)alloc(2048ull * 1024 * 4);
  float* qg   = (float*)alloc(2048ull * 1024 * 4);
  u16* khP   = (u16*)alloc(32ull * 1024 * 64 * 2);
  u16* krP   = (u16*)alloc(32ull * 2056 * 64 * 2);
  u16* qhP   = (u16*)alloc(32ull * 1024 * 64 * 2);
  u16* qgP   = (u16*)alloc(32ull * 1024 * 64 * 2);
  u16* vTb   = (u16*)alloc(32ull * 64 * 1024 * 2);
  float* tsegb = (float*)alloc(2048ull * 4);
  float* rwk2 = (float*)alloc(32ull * 1024 * 4);
  float* rrk2 = (float*)alloc(32ull * 2056 * 4);
  float* ef1h = (float*)alloc(1024ull * 2 * 16 * 2 * 4);
  float* ef1g = (float*)alloc(1024ull * 2 * 16 * 2 * 4);
  u16* vech  = (u16*)alloc(2048ull * 1024 * 2);
  u16* vecg  = (u16*)alloc(2048ull * 1024 * 2);
  float* tmp  = (float*)alloc(2048ull * 4096 * 4);
  float* pml  = (float*)alloc(32ull * 16 * 4 * 64 * 2 * 4);
  float* x1f  = (float*)alloc(2048ull * 1024 * 4);
  u16* x1b   = (u16*)alloc(2048ull * 1024 * 2);
  u16* hid   = (u16*)alloc(2048ull * 4096 * 2);
  float* po   = tmp;   // attention partials reuse tmp (33.5 MB, stream-ordered safe)

  const dim3 blk(256);

  // --- convert activations / weights to bf16 (weights to B^T [N,K] layout) ---
  cvt_bf16_kernel<<<2048, blk, 0, stream>>>(h, hb, 524288);
  cvt_bf16_kernel<<<2048, blk, 0, stream>>>(g, gbuf, 524288);
  cvt_bf16_kernel<<<4096, blk, 0, stream>>>(r, rb, 1048576);
  cvt_bf16_kernel<<<1024, blk, 0, stream>>>(wo, woB, 262144);
  transpose_cvt_kernel<<<dim3(32, 32), blk, 0, stream>>>(wq, wqT, 1024, 1024);
  transpose_cvt_kernel<<<dim3(32, 32), blk, 0, stream>>>(wk, wkT, 1024, 1024);
  transpose_cvt_kernel<<<dim3(32, 32), blk, 0, stream>>>(wv, wvT, 1024, 1024);
  transpose_cvt_kernel<<<dim3(32, 32), blk, 0, stream>>>(wr, wrT, 1024, 1024);
  transpose_cvt_kernel<<<dim3(128, 32), blk, 0, stream>>>(fw1, w1T, 1024, 4096);
  transpose_cvt_kernel<<<dim3(32, 128), blk, 0, stream>>>(fw2, w2T, 4096, 1024);

  // --- shared projections (64-row tiles -> 256/512-block grids) ---
  gemm_bt64<<<dim3(8, 32), blk, 0, stream>>>(hb, wkT, kh, 2048, 1024, 1024);
  gemm_bt64<<<dim3(8, 32), blk, 0, stream>>>(hb, wvT, vh, 2048, 1024, 1024);
  gemm_bt64<<<dim3(8, 64), blk, 0, stream>>>(rb, wrT, kr, 4096, 1024, 1024);
  gemm_bt64<<<dim3(8, 32), blk, 0, stream>>>(hb, wqT, qh, 2048, 1024, 1024);
  gemm_bt64<<<dim3(8, 32), blk, 0, stream>>>(gbuf, wqT, qg, 2048, 1024, 1024);

  // --- attention precomputes ---
  tseg_kernel<<<8, blk, 0, stream>>>(segmat, tsegb);
  headperm_kernel<<<dim3(64, 32), blk, 0, stream>>>(kh, khP, 1024, 1024);
  headperm_kernel<<<dim3(129, 32), blk, 0, stream>>>(kr, krP, 2048, 2056);
  headperm_kernel<<<dim3(64, 32), blk, 0, stream>>>(qh, qhP, 1024, 1024);
  headperm_kernel<<<dim3(64, 32), blk, 0, stream>>>(qg, qgP, 1024, 1024);
  vtrans_kernel<<<dim3(16, 32), blk, 0, stream>>>(vh, vTb);
  rowdot_kernel<<<8192, blk, 0, stream>>>(kh, rwb, rwk2, 32768, 1024, 0);
  rowdot_kernel<<<16384, blk, 0, stream>>>(kr, rrb, rrk2, 65536, 2056, 3);
  ef1_kernel<<<8192, blk, 0, stream>>>(qh, rsb, sege, ef1h, 32768);
  ef1_kernel<<<8192, blk, 0, stream>>>(qg, rsb, sege, ef1g, 32768);

  // --- per-stream: attention (split + combine) -> wo -> LN -> FFN -> LN ---
  for (int s = 0; s < 2; ++s) {
    const u16* qPs    = s ? qgP : qhP;
    const float* ef1s = s ? ef1g : ef1h;
    const float* res  = s ? g : h;
    u16* vec          = s ? vecg : vech;
    float* outp       = out + (size_t)s * 2048 * 1024;

    attn_mfma_kernel<<<dim3(64, 32), blk, 0, stream>>>(qPs, khP, krP, vTb, rwk2, rrk2,
                                                       ef1s, tsegb, po, pml, s);
    attn_combine_kernel<<<dim3(16, 32), blk, 0, stream>>>(po, pml, vec, s);
    gemm_bt64<<<dim3(8, 32), blk, 0, stream>>>(vec, woB, tmp, 2048, 1024, 1024);
    ln_kernel<<<2048, blk, 0, stream>>>(tmp, res, nullptr, lga, lba, x1f, x1b);
    gemm_bt_gelu<<<dim3(32, 16), blk, 0, stream>>>(x1b, w1T, fb1, hid, 2048, 4096, 1024);
    gemm_bt64<<<dim3(8, 32), blk, 0, stream>>>(hid, w2T, tmp, 2048, 1024, 4096);
    ln_kernel<<<2048, blk, 0, stream>>>(tmp, x1f, fb2, lgf, lbf, outp, nullptr);
  }
}